// Round 3
// baseline (608.342 us; speedup 1.0000x reference)
//
#include <hip/hip_runtime.h>

// Problem constants (from reference)
constexpr int M_ROWS = 8 * 64;   // B*N = 512 keyword rows
constexpr int D_IN   = 768;      // d_model
constexpr int T_DIM  = 512;      // CLIP text dim
constexpr int V_SIZE = 49408;    // vocab
constexpr float EPS  = 1e-8f;

// ---------------- Kernel 1: projection kw = audio @ W + b ----------------
// grid 128 blocks x 256 threads; each block does 4 rows x 512 cols
__global__ __launch_bounds__(256) void proj_kernel(
    const float* __restrict__ audio, const float* __restrict__ W,
    const float* __restrict__ bias, float* __restrict__ kw) {
  __shared__ float a[4][D_IN];  // 12 KB
  const int tid = threadIdx.x;
  const int m0 = blockIdx.x * 4;

  const float4* src4 = reinterpret_cast<const float4*>(audio + (size_t)m0 * D_IN);
  float4* a4 = reinterpret_cast<float4*>(&a[0][0]);
  #pragma unroll
  for (int i = 0; i < 3; ++i) a4[tid + 256 * i] = src4[tid + 256 * i];
  __syncthreads();

  const int t0 = tid, t1 = tid + 256;
  float acc[4][2] = {};
  #pragma unroll 4
  for (int d = 0; d < D_IN; ++d) {
    const float w0 = W[(size_t)d * T_DIM + t0];
    const float w1 = W[(size_t)d * T_DIM + t1];
    #pragma unroll
    for (int r = 0; r < 4; ++r) {
      acc[r][0] = fmaf(a[r][d], w0, acc[r][0]);
      acc[r][1] = fmaf(a[r][d], w1, acc[r][1]);
    }
  }
  const float b0 = bias[t0], b1 = bias[t1];
  #pragma unroll
  for (int r = 0; r < 4; ++r) {
    kw[(size_t)(m0 + r) * T_DIM + t0] = acc[r][0] + b0;
    kw[(size_t)(m0 + r) * T_DIM + t1] = acc[r][1] + b1;
  }
}

// ---------------- Kernel 2: token_emb row inverse norms ----------------
// one wave per vocab row; grid V/4 blocks x 256 threads
__global__ __launch_bounds__(256) void norm_kernel(
    const float* __restrict__ emb, float* __restrict__ inv_norm) {
  const int wave = threadIdx.x >> 6;
  const int lane = threadIdx.x & 63;
  const int v = blockIdx.x * 4 + wave;
  const float4* row = reinterpret_cast<const float4*>(emb + (size_t)v * T_DIM);
  const float4 x = row[lane];
  const float4 y = row[lane + 64];
  float ss = x.x * x.x + x.y * x.y + x.z * x.z + x.w * x.w +
             y.x * y.x + y.y * y.y + y.z * y.z + y.w * y.w;
  #pragma unroll
  for (int off = 32; off > 0; off >>= 1) ss += __shfl_xor(ss, off);
  if (lane == 0) inv_norm[v] = 1.0f / fmaxf(sqrtf(ss), EPS);
}

// ---------------- Kernel 3: scoring GEMM + fused argmax ----------------
// scores = (kw @ emb^T) * inv_norm[col]; per-row argmax via packed atomicMax.
// Tile: 128 rows x 128 cols, K staged in chunks of 32. 256 threads, 8x8/thread.
constexpr int KC = 32;
constexpr int LDS_STRIDE = 132;  // 128 + 4 pad (keeps 16B alignment, spreads banks)

__device__ inline unsigned int f32_sortable(float f) {
  unsigned int u = __float_as_uint(f);
  return (u & 0x80000000u) ? ~u : (u | 0x80000000u);
}

__device__ inline unsigned long long shfl_xor_u64(unsigned long long x, int mask) {
  unsigned int lo = (unsigned int)(x & 0xFFFFFFFFull);
  unsigned int hi = (unsigned int)(x >> 32);
  lo = __shfl_xor(lo, mask);
  hi = __shfl_xor(hi, mask);
  return ((unsigned long long)hi << 32) | (unsigned long long)lo;
}

__global__ __launch_bounds__(256) void score_kernel(
    const float* __restrict__ kw, const float* __restrict__ emb,
    const float* __restrict__ inv_norm, unsigned long long* __restrict__ best) {
  __shared__ float kwT[KC][LDS_STRIDE];   // [k][m] 16.9 KB
  __shared__ float embT[KC][LDS_STRIDE];  // [k][v] 16.9 KB

  const int tid = threadIdx.x;
  const int n0 = blockIdx.x * 128;  // vocab tile base (386 tiles)
  const int m0 = blockIdx.y * 128;  // row tile base (4 tiles)

  const int rg = tid >> 4;       // 0..15 row group
  const int cg = tid & 15;       // 0..15 col group
  const int r0 = rg * 8;
  const int c0 = cg * 8;

  // loader mapping: 128 rows x 32 k per tile; thread covers float4 at
  // (row = lm + 32p, k = lk..lk+3)
  const int lm = tid >> 3;
  const int lk = (tid & 7) * 4;

  float acc[8][8] = {};

  for (int kc = 0; kc < T_DIM; kc += KC) {
    #pragma unroll
    for (int p = 0; p < 4; ++p) {
      const int r = lm + 32 * p;
      const float4 v = *reinterpret_cast<const float4*>(
          &kw[(size_t)(m0 + r) * T_DIM + kc + lk]);
      kwT[lk + 0][r] = v.x; kwT[lk + 1][r] = v.y;
      kwT[lk + 2][r] = v.z; kwT[lk + 3][r] = v.w;
      const float4 e = *reinterpret_cast<const float4*>(
          &emb[(size_t)(n0 + r) * T_DIM + kc + lk]);
      embT[lk + 0][r] = e.x; embT[lk + 1][r] = e.y;
      embT[lk + 2][r] = e.z; embT[lk + 3][r] = e.w;
    }
    __syncthreads();

    #pragma unroll 4
    for (int k = 0; k < KC; ++k) {
      const float4 a0 = *reinterpret_cast<const float4*>(&kwT[k][r0]);
      const float4 a1 = *reinterpret_cast<const float4*>(&kwT[k][r0 + 4]);
      const float4 b0 = *reinterpret_cast<const float4*>(&embT[k][c0]);
      const float4 b1 = *reinterpret_cast<const float4*>(&embT[k][c0 + 4]);
      const float av[8] = {a0.x, a0.y, a0.z, a0.w, a1.x, a1.y, a1.z, a1.w};
      const float bv[8] = {b0.x, b0.y, b0.z, b0.w, b1.x, b1.y, b1.z, b1.w};
      #pragma unroll
      for (int i = 0; i < 8; ++i)
        #pragma unroll
        for (int j = 0; j < 8; ++j)
          acc[i][j] = fmaf(av[i], bv[j], acc[i][j]);
    }
    __syncthreads();
  }

  // epilogue: scale by emb inv-norm, pack (score, ~idx), row-reduce, atomicMax
  float inv[8];
  #pragma unroll
  for (int j = 0; j < 8; ++j) inv[j] = inv_norm[n0 + c0 + j];

  #pragma unroll
  for (int i = 0; i < 8; ++i) {
    unsigned long long pk = 0;
    #pragma unroll
    for (int j = 0; j < 8; ++j) {
      const float s = acc[i][j] * inv[j];
      const unsigned int su = f32_sortable(s);
      const unsigned long long p =
          ((unsigned long long)su << 32) |
          (unsigned long long)(0xFFFFFFFFu - (unsigned)(n0 + c0 + j));
      if (p > pk) pk = p;
    }
    // reduce across the 16 col-groups (lanes differing in bits 0..3)
    #pragma unroll
    for (int off = 1; off < 16; off <<= 1) {
      const unsigned long long o = shfl_xor_u64(pk, off);
      if (o > pk) pk = o;
    }
    if (cg == 0) atomicMax(&best[m0 + r0 + i], pk);
  }
}

// ---------------- Kernel 4: gather out[row] = token_emb[best[row]] ----------------
__global__ __launch_bounds__(128) void gather_kernel(
    const float* __restrict__ emb, const unsigned long long* __restrict__ best,
    float* __restrict__ out) {
  const int row = blockIdx.x;
  const unsigned int idx =
      0xFFFFFFFFu - (unsigned int)(best[row] & 0xFFFFFFFFull);
  const float4* src = reinterpret_cast<const float4*>(emb + (size_t)idx * T_DIM);
  float4* dst = reinterpret_cast<float4*>(out + (size_t)row * T_DIM);
  dst[threadIdx.x] = src[threadIdx.x];
}

// ---------------- launch ----------------
extern "C" void kernel_launch(void* const* d_in, const int* in_sizes, int n_in,
                              void* d_out, int out_size, void* d_ws, size_t ws_size,
                              hipStream_t stream) {
  const float* audio = (const float*)d_in[0];  // [512, 768]
  const float* Wp    = (const float*)d_in[1];  // [768, 512]
  const float* bp    = (const float*)d_in[2];  // [512]
  const float* emb   = (const float*)d_in[3];  // [49408, 512]
  float* out = (float*)d_out;                  // [512, 512]

  char* ws = (char*)d_ws;
  float* kw       = (float*)ws;                                   // 1 MB
  float* inv_norm = (float*)(ws + (size_t)M_ROWS * T_DIM * 4);    // 193 KB
  unsigned long long* best =
      (unsigned long long*)(ws + ((size_t)M_ROWS * T_DIM + V_SIZE) * 4);  // 4 KB

  hipMemsetAsync(best, 0, M_ROWS * sizeof(unsigned long long), stream);

  proj_kernel<<<M_ROWS / 4, 256, 0, stream>>>(audio, Wp, bp, kw);
  norm_kernel<<<V_SIZE / 4, 256, 0, stream>>>(emb, inv_norm);
  score_kernel<<<dim3(V_SIZE / 128, M_ROWS / 128), 256, 0, stream>>>(
      kw, emb, inv_norm, best);
  gather_kernel<<<M_ROWS, 128, 0, stream>>>(emb, best, out);
}

// Round 4
// 383.936 us; speedup vs baseline: 1.5845x; 1.5845x over previous
//
#include <hip/hip_runtime.h>

// Problem constants
constexpr int M_ROWS = 512;      // B*N keyword rows
constexpr int D_IN   = 768;
constexpr int T_DIM  = 512;
constexpr int V_SIZE = 49408;
constexpr float EPS  = 1e-8f;

typedef short bf16x8 __attribute__((ext_vector_type(8)));
typedef float f32x16 __attribute__((ext_vector_type(16)));

__device__ inline unsigned short bf16_rne(float f) {
  unsigned int u = __float_as_uint(f);
  u += 0x7FFFu + ((u >> 16) & 1u);
  return (unsigned short)(u >> 16);
}
__device__ inline float bf16_f32(unsigned short h) {
  return __uint_as_float(((unsigned int)h) << 16);
}
__device__ inline unsigned int f32_sortable(float f) {
  unsigned int u = __float_as_uint(f);
  return (u & 0x80000000u) ? ~u : (u | 0x80000000u);
}
__device__ inline unsigned long long shfl_xor_u64(unsigned long long x, int mask) {
  unsigned int lo = (unsigned int)(x & 0xFFFFFFFFull);
  unsigned int hi = (unsigned int)(x >> 32);
  lo = __shfl_xor(lo, mask);
  hi = __shfl_xor(hi, mask);
  return ((unsigned long long)hi << 32) | (unsigned long long)lo;
}

// ---------------- Kernel 1: proj kw = audio @ W + b, write bf16 hi/lo ----------------
__global__ __launch_bounds__(256) void proj_kernel(
    const float* __restrict__ audio, const float* __restrict__ W,
    const float* __restrict__ bias, unsigned short* __restrict__ kwH,
    unsigned short* __restrict__ kwL) {
  __shared__ float a[4][D_IN];  // 12 KB
  const int tid = threadIdx.x;
  const int m0 = blockIdx.x * 4;

  const float4* src4 = reinterpret_cast<const float4*>(audio + (size_t)m0 * D_IN);
  float4* a4 = reinterpret_cast<float4*>(&a[0][0]);
  #pragma unroll
  for (int i = 0; i < 3; ++i) a4[tid + 256 * i] = src4[tid + 256 * i];
  __syncthreads();

  const int t0 = tid, t1 = tid + 256;
  float acc[4][2] = {};
  #pragma unroll 4
  for (int d = 0; d < D_IN; ++d) {
    const float w0 = W[(size_t)d * T_DIM + t0];
    const float w1 = W[(size_t)d * T_DIM + t1];
    #pragma unroll
    for (int r = 0; r < 4; ++r) {
      acc[r][0] = fmaf(a[r][d], w0, acc[r][0]);
      acc[r][1] = fmaf(a[r][d], w1, acc[r][1]);
    }
  }
  const float b0 = bias[t0], b1 = bias[t1];
  #pragma unroll
  for (int r = 0; r < 4; ++r) {
    const float v0 = acc[r][0] + b0;
    const float v1 = acc[r][1] + b1;
    const unsigned short h0 = bf16_rne(v0);
    const unsigned short h1 = bf16_rne(v1);
    kwH[(size_t)(m0 + r) * T_DIM + t0] = h0;
    kwH[(size_t)(m0 + r) * T_DIM + t1] = h1;
    kwL[(size_t)(m0 + r) * T_DIM + t0] = bf16_rne(v0 - bf16_f32(h0));
    kwL[(size_t)(m0 + r) * T_DIM + t1] = bf16_rne(v1 - bf16_f32(h1));
  }
}

// ---------------- Kernel 2: token_emb row inverse norms ----------------
__global__ __launch_bounds__(256) void norm_kernel(
    const float* __restrict__ emb, float* __restrict__ inv_norm) {
  const int wave = threadIdx.x >> 6;
  const int lane = threadIdx.x & 63;
  const int v = blockIdx.x * 4 + wave;
  const float4* row = reinterpret_cast<const float4*>(emb + (size_t)v * T_DIM);
  const float4 x = row[lane];
  const float4 y = row[lane + 64];
  float ss = x.x * x.x + x.y * x.y + x.z * x.z + x.w * x.w +
             y.x * y.x + y.y * y.y + y.z * y.z + y.w * y.w;
  #pragma unroll
  for (int off = 32; off > 0; off >>= 1) ss += __shfl_xor(ss, off);
  if (lane == 0) inv_norm[v] = 1.0f / fmaxf(sqrtf(ss), EPS);
}

// ---------------- Kernel 3: MFMA scoring + fused argmax ----------------
// score[row, v] = kw[row,:] . (emb[v,:] * inv_norm[v])  via 3-term bf16 split.
// Block: BM=256 x BN=128, K=512 in chunks of 32. 4 waves, each 64 rows x 128 cols.
// emb f32 -> scaled bf16 hi/lo converted in-kernel, stored FRAGMENT-ORDERED in LDS
// (both ds_write and ds_read are lane-linear 16B => zero bank conflicts).
__global__ __launch_bounds__(256, 2) void score_kernel(
    const unsigned short* __restrict__ kwH, const unsigned short* __restrict__ kwL,
    const float* __restrict__ emb, const float* __restrict__ inv_norm,
    unsigned long long* __restrict__ best) {
  // frag f = ks*4+nt; slot layout [frag][lane][8]: col=lane&31, k-half=lane>>5
  __shared__ short ldsH[2][8][64][8];  // 16 KB
  __shared__ short ldsL[2][8][64][8];  // 16 KB

  const int tid  = threadIdx.x;
  const int lane = tid & 63;
  const int w    = tid >> 6;
  const int n0   = blockIdx.x * 128;
  const int m0   = blockIdx.y * 256;

  // staging constants: 2 lane-slots per thread, col fixed across all K-chunks
  size_t sg[2];
  float  ssc[2];
  int    sof[2];
  #pragma unroll
  for (int p = 0; p < 2; ++p) {
    const int s  = tid + 256 * p;
    const int ls = s & 63;
    const int nt = (s >> 6) & 3;
    const int ks = (s >> 8) & 1;
    const int col  = nt * 32 + (ls & 31);
    const int krel = ks * 16 + (ls >> 5) * 8;
    sg[p]  = (size_t)(n0 + col) * T_DIM + krel;
    ssc[p] = inv_norm[n0 + col];
    sof[p] = ((ks * 4 + nt) * 64 + ls) * 8;
  }

  // A-operand global element bases (kw row-major bf16, 8 consecutive k per lane)
  const int kh = (lane >> 5) * 8;
  size_t aOff[2];
  #pragma unroll
  for (int rt = 0; rt < 2; ++rt)
    aOff[rt] = (size_t)(m0 + w * 64 + rt * 32 + (lane & 31)) * T_DIM + kh;

  f32x16 acc[2][4];
  #pragma unroll
  for (int rt = 0; rt < 2; ++rt)
    #pragma unroll
    for (int ct = 0; ct < 4; ++ct)
      #pragma unroll
      for (int i = 0; i < 16; ++i) acc[rt][ct][i] = 0.0f;

  float ld[2][8];

  // ---- stage chunk 0 ----
  #pragma unroll
  for (int p = 0; p < 2; ++p) {
    const float4 x0 = *reinterpret_cast<const float4*>(&emb[sg[p]]);
    const float4 x1 = *reinterpret_cast<const float4*>(&emb[sg[p] + 4]);
    ld[p][0] = x0.x; ld[p][1] = x0.y; ld[p][2] = x0.z; ld[p][3] = x0.w;
    ld[p][4] = x1.x; ld[p][5] = x1.y; ld[p][6] = x1.z; ld[p][7] = x1.w;
  }
  {
    short* hw = &ldsH[0][0][0][0];
    short* lw = &ldsL[0][0][0][0];
    #pragma unroll
    for (int p = 0; p < 2; ++p) {
      bf16x8 hv, lv;
      #pragma unroll
      for (int j = 0; j < 8; ++j) {
        const float x = ld[p][j] * ssc[p];
        const unsigned short h = bf16_rne(x);
        hv[j] = (short)h;
        lv[j] = (short)bf16_rne(x - bf16_f32(h));
      }
      *reinterpret_cast<bf16x8*>(hw + sof[p]) = hv;
      *reinterpret_cast<bf16x8*>(lw + sof[p]) = lv;
    }
  }
  __syncthreads();

  // ---- main loop: 16 K-chunks of 32 ----
  for (int ci = 0; ci < 16; ++ci) {
    const int buf = ci & 1;

    // early-issue global loads for next chunk (latency hides under MFMA)
    if (ci < 15) {
      #pragma unroll
      for (int p = 0; p < 2; ++p) {
        const size_t g = sg[p] + (size_t)(ci + 1) * 32;
        const float4 x0 = *reinterpret_cast<const float4*>(&emb[g]);
        const float4 x1 = *reinterpret_cast<const float4*>(&emb[g + 4]);
        ld[p][0] = x0.x; ld[p][1] = x0.y; ld[p][2] = x0.z; ld[p][3] = x0.w;
        ld[p][4] = x1.x; ld[p][5] = x1.y; ld[p][6] = x1.z; ld[p][7] = x1.w;
      }
    }

    // compute chunk ci from buf
    const short* hq = &ldsH[buf][0][0][0];
    const short* lq = &ldsL[buf][0][0][0];
    #pragma unroll
    for (int ks = 0; ks < 2; ++ks) {
      const size_t ak = (size_t)(ci * 32 + ks * 16);
      bf16x8 aH[2], aL[2];
      #pragma unroll
      for (int rt = 0; rt < 2; ++rt) {
        aH[rt] = *reinterpret_cast<const bf16x8*>(&kwH[aOff[rt] + ak]);
        aL[rt] = *reinterpret_cast<const bf16x8*>(&kwL[aOff[rt] + ak]);
      }
      #pragma unroll
      for (int ct = 0; ct < 4; ++ct) {
        const bf16x8 bH = *reinterpret_cast<const bf16x8*>(hq + ((ks * 4 + ct) * 64 + lane) * 8);
        const bf16x8 bL = *reinterpret_cast<const bf16x8*>(lq + ((ks * 4 + ct) * 64 + lane) * 8);
        #pragma unroll
        for (int rt = 0; rt < 2; ++rt) {
          acc[rt][ct] = __builtin_amdgcn_mfma_f32_32x32x16_bf16(aH[rt], bH, acc[rt][ct], 0, 0, 0);
          acc[rt][ct] = __builtin_amdgcn_mfma_f32_32x32x16_bf16(aH[rt], bL, acc[rt][ct], 0, 0, 0);
          acc[rt][ct] = __builtin_amdgcn_mfma_f32_32x32x16_bf16(aL[rt], bH, acc[rt][ct], 0, 0, 0);
        }
      }
    }

    // convert + write next chunk into buf^1 (its readers finished at barrier ci-1)
    if (ci < 15) {
      short* hw = &ldsH[buf ^ 1][0][0][0];
      short* lw = &ldsL[buf ^ 1][0][0][0];
      #pragma unroll
      for (int p = 0; p < 2; ++p) {
        bf16x8 hv, lv;
        #pragma unroll
        for (int j = 0; j < 8; ++j) {
          const float x = ld[p][j] * ssc[p];
          const unsigned short h = bf16_rne(x);
          hv[j] = (short)h;
          lv[j] = (short)bf16_rne(x - bf16_f32(h));
        }
        *reinterpret_cast<bf16x8*>(hw + sof[p]) = hv;
        *reinterpret_cast<bf16x8*>(lw + sof[p]) = lv;
      }
    }
    __syncthreads();
  }

  // ---- epilogue: per-row argmax. C/D: col=lane&31, row=(reg&3)+8*(reg>>2)+4*(lane>>5)
  #pragma unroll
  for (int rt = 0; rt < 2; ++rt) {
    const int rowbase = m0 + w * 64 + rt * 32 + 4 * (lane >> 5);
    #pragma unroll
    for (int reg = 0; reg < 16; ++reg) {
      const int row = rowbase + (reg & 3) + 8 * (reg >> 2);
      unsigned long long pk = 0;
      #pragma unroll
      for (int ct = 0; ct < 4; ++ct) {
        const float s = acc[rt][ct][reg];
        const unsigned long long p =
            ((unsigned long long)f32_sortable(s) << 32) |
            (unsigned long long)(0xFFFFFFFFu - (unsigned)(n0 + ct * 32 + (lane & 31)));
        if (p > pk) pk = p;
      }
      #pragma unroll
      for (int off = 1; off < 32; off <<= 1) {
        const unsigned long long o = shfl_xor_u64(pk, off);
        if (o > pk) pk = o;
      }
      if ((lane & 31) == 0) atomicMax(&best[row], pk);
    }
  }
}

// ---------------- Kernel 4: gather out[row] = token_emb[best[row]] ----------------
__global__ __launch_bounds__(128) void gather_kernel(
    const float* __restrict__ emb, const unsigned long long* __restrict__ best,
    float* __restrict__ out) {
  const int row = blockIdx.x;
  const unsigned int idx =
      0xFFFFFFFFu - (unsigned int)(best[row] & 0xFFFFFFFFull);
  const float4* src = reinterpret_cast<const float4*>(emb + (size_t)idx * T_DIM);
  float4* dst = reinterpret_cast<float4*>(out + (size_t)row * T_DIM);
  dst[threadIdx.x] = src[threadIdx.x];
}

// ---------------- launch ----------------
extern "C" void kernel_launch(void* const* d_in, const int* in_sizes, int n_in,
                              void* d_out, int out_size, void* d_ws, size_t ws_size,
                              hipStream_t stream) {
  const float* audio = (const float*)d_in[0];  // [512, 768]
  const float* Wp    = (const float*)d_in[1];  // [768, 512]
  const float* bp    = (const float*)d_in[2];  // [512]
  const float* emb   = (const float*)d_in[3];  // [49408, 512]
  float* out = (float*)d_out;                  // [512, 512]

  char* ws = (char*)d_ws;
  unsigned short* kwH = (unsigned short*)ws;                         // 512 KB
  unsigned short* kwL = kwH + (size_t)M_ROWS * T_DIM;                // 512 KB
  float* inv_norm = (float*)(ws + (size_t)2 * M_ROWS * T_DIM * 2);   // 193 KB
  unsigned long long* best = (unsigned long long*)(inv_norm + V_SIZE);  // 4 KB

  hipMemsetAsync(best, 0, M_ROWS * sizeof(unsigned long long), stream);

  proj_kernel<<<M_ROWS / 4, 256, 0, stream>>>(audio, Wp, bp, kwH, kwL);
  norm_kernel<<<V_SIZE / 4, 256, 0, stream>>>(emb, inv_norm);
  score_kernel<<<dim3(V_SIZE / 128, M_ROWS / 256), 256, 0, stream>>>(
      kwH, kwL, emb, inv_norm, best);
  gather_kernel<<<M_ROWS, 128, 0, stream>>>(emb, best, out);
}